// Round 8
// baseline (162.337 us; speedup 1.0000x reference)
//
#include <hip/hip_runtime.h>

#define BB 8
#define NN 1024
#define CC 128
#define GG 4
#define LL 8
#define GD 64

typedef __attribute__((ext_vector_type(8))) short short8;
typedef __attribute__((ext_vector_type(4))) short short4v;
typedef __attribute__((ext_vector_type(4))) float floatx4;

__device__ __forceinline__ short f2b(float f) {
  union { float f; unsigned u; } c; c.f = f;
  unsigned u = c.u;
  return (short)((u + 0x7FFFu + ((u >> 16) & 1u)) >> 16);   // RNE fp32->bf16
}
__device__ __forceinline__ float b2f(short s) {
  union { unsigned u; float f; } c; c.u = ((unsigned)(unsigned short)s) << 16;
  return c.f;
}
__device__ __forceinline__ void split2(float v, short& hi, short& lo) {
  short h = f2b(v);
  hi = h;
  lo = f2b(v - b2f(h));
}

// packed fp32x2 -> bf16x2 (dword: low=a, high=b)
#if __has_builtin(__builtin_amdgcn_cvt_pk_bf16_f32)
__device__ __forceinline__ unsigned pk2(float a, float b) {
  auto r = __builtin_amdgcn_cvt_pk_bf16_f32(a, b);
  unsigned u; __builtin_memcpy(&u, &r, 4); return u;
}
#else
__device__ __forceinline__ unsigned pk2(float a, float b) {
  return (unsigned)(unsigned short)f2b(a) | ((unsigned)(unsigned short)f2b(b) << 16);
}
#endif

#if __has_builtin(__builtin_amdgcn_exp2f)
#define EXP2(x) __builtin_amdgcn_exp2f(x)
#else
#define EXP2(x) exp2f(x)
#endif

// ---------------- Kernel A: projections via bf16x3 MFMA (no LDS) ----------
__global__ __launch_bounds__(256) void proj_kernel(
    const float* __restrict__ x, const float* __restrict__ Wq,
    const float* __restrict__ Wk, const float* __restrict__ Wv,
    short* __restrict__ qb, short* __restrict__ kb, short* __restrict__ vtb)
{
  const int t = threadIdx.x;
  const int nt = blockIdx.x & 3;
  const int mt = blockIdx.x >> 2;
  const int w = t >> 6;
  const int lane = t & 63;
  const int ln = lane & 15;
  const int hq = lane >> 4;
  const int arow = mt * 64 + w * 16 + ln;

  const float* wbase = (nt == 0) ? Wq : (nt == 1) ? Wk : (Wv + (nt - 2) * 64 * 128);
  const floatx4 zf = {0.f, 0.f, 0.f, 0.f};
  floatx4 acc[4] = {zf, zf, zf, zf};

  #pragma unroll
  for (int kc = 0; kc < 4; ++kc) {
    const float* xp = x + (long)arow * 128 + kc * 32 + hq * 8;
    float4 a0 = *(const float4*)xp;
    float4 a1 = *(const float4*)(xp + 4);
    union { short s[8]; short8 v; } Ah, Al;
    float av[8] = {a0.x,a0.y,a0.z,a0.w,a1.x,a1.y,a1.z,a1.w};
    #pragma unroll
    for (int z = 0; z < 8; ++z) split2(av[z], Ah.s[z], Al.s[z]);
    #pragma unroll
    for (int ns = 0; ns < 4; ++ns) {
      const float* wp = wbase + (long)(ns * 16 + ln) * 128 + kc * 32 + hq * 8;
      float4 b0 = *(const float4*)wp;
      float4 b1 = *(const float4*)(wp + 4);
      union { short s[8]; short8 v; } Bh, Bl;
      float bv[8] = {b0.x,b0.y,b0.z,b0.w,b1.x,b1.y,b1.z,b1.w};
      #pragma unroll
      for (int z = 0; z < 8; ++z) split2(bv[z], Bh.s[z], Bl.s[z]);
      acc[ns] = __builtin_amdgcn_mfma_f32_16x16x32_bf16(Ah.v, Bh.v, acc[ns], 0,0,0);
      acc[ns] = __builtin_amdgcn_mfma_f32_16x16x32_bf16(Al.v, Bh.v, acc[ns], 0,0,0);
      acc[ns] = __builtin_amdgcn_mfma_f32_16x16x32_bf16(Ah.v, Bl.v, acc[ns], 0,0,0);
    }
  }

  if (nt < 2) {
    short* dst = (nt == 0) ? qb : kb;
    #pragma unroll
    for (int ns = 0; ns < 4; ++ns) {
      int col = ns * 16 + ln;
      #pragma unroll
      for (int reg = 0; reg < 4; ++reg) {
        int row = mt * 64 + w * 16 + hq * 4 + reg;
        dst[(long)row * 64 + col] = f2b(acc[ns][reg]);
      }
    }
  } else {
    int b = mt >> 4;
    int tok = (mt * 64 + w * 16 + hq * 4) & 1023;
    #pragma unroll
    for (int ns = 0; ns < 4; ++ns) {
      int cv = (nt - 2) * 64 + ns * 16 + ln;
      union { short s[4]; short4v v; } o;
      #pragma unroll
      for (int reg = 0; reg < 4; ++reg) o.s[reg] = f2b(acc[ns][reg]);
      *(short4v*)(vtb + ((long)b * CC + cv) * NN + tok) = o.v;
    }
  }
}

// ---------------- Kernel B: MFMA attention, batch-pair blocks ----------
// grid 1024: sp = bx&3 (j-split), itile = (bx>>2)&63, bg = bx>>8 (b-pair).
// Per 32-j tile (2 barriers): stage masks->mrec[p] | bar1 | QK (2 b) -> arec |
// bar2 | mix (mw shared across 2 b x 2 l) + exp2 + pk-bf16 + PV (4 mfma).
#define IT 16
#define JT 32
#define SPLIT 4
#define JSPAN 256
#define NTL 8
#define ARP 132   // dwords per i-row of arec: 32j*4g + 4
#define AR1 (IT * ARP)
#define MRP 100   // dwords per i-row of mrec: 32j*3 + 4

__global__ __launch_bounds__(256, 4) void attn_kernel(
    const short* __restrict__ qb, const short* __restrict__ kb,
    const short* __restrict__ vtb, const float* __restrict__ masks,
    const float* __restrict__ mask_proj,
    float* __restrict__ pnum, float* __restrict__ pden3)
{
  __shared__ float arec[2 * IT * ARP];    // 16896 B (b0 | b1)
  __shared__ float mrec[2][IT * MRP];     // 12800 B (double-buffered)

  const int t = threadIdx.x;
  const int sp = blockIdx.x & 3;
  const int itile = (blockIdx.x >> 2) & 63;
  const int bg = blockIdx.x >> 8;
  const int b0 = bg * 2;
  const int i0 = itile * IT;

  const int w = t >> 6;          // wave id: g (QK) ; l-pair owner (mix+PV)
  const int lane = t & 63;
  const int ln = lane & 15;
  const int hq = lane >> 4;
  const int l0 = 2 * w, l1 = 2 * w + 1;

  // Q A-fragments for b0,b1 (g = w), K-dim zero-padded 16->32
  short8 qf[2];
  #pragma unroll
  for (int b2 = 0; b2 < 2; ++b2) {
    union { short s[8]; short8 v; } qq;
    #pragma unroll
    for (int z = 0; z < 8; ++z) qq.s[z] = 0;
    if (hq < 2)
      qq.v = *(const short8*)(qb + ((long)((b0 + b2) * NN + i0 + ln)) * GD + w * 16 + hq * 8);
    qf[b2] = qq.v;
  }
  // mix constants in exp2 domain
  const float LOG2E = 1.44269504088896340736f;
  float ycA[3][4], ycB[3][4];
  #pragma unroll
  for (int m = 0; m < 3; ++m)
    #pragma unroll
    for (int g = 0; g < 4; ++g) {
      ycA[m][g] = mask_proj[m * 32 + g * 8 + l0] * LOG2E;
      ycB[m][g] = mask_proj[m * 32 + g * 8 + l1] * LOG2E;
    }

  const floatx4 zf = {0.f, 0.f, 0.f, 0.f};
  floatx4 pv00 = zf, pv01 = zf, pv10 = zf, pv11 = zf;
  float d00 = 0.f, d01 = 0.f, d10 = 0.f, d11 = 0.f;

  const short* kbase0 = kb + (long)b0 * NN * GD;
  const short* kbase1 = kb + (long)(b0 + 1) * NN * GD;
  const short* vb00 = vtb + ((long)b0 * CC + l0 * 16 + ln) * NN;
  const short* vb01 = vtb + ((long)b0 * CC + l1 * 16 + ln) * NN;
  const short* vb10 = vb00 + (long)CC * NN;
  const short* vb11 = vb01 + (long)CC * NN;

  for (int jt = 0; jt < NTL; ++jt) {
    const int j0 = sp * JSPAN + jt * JT;
    float* mrp = mrec[jt & 1];

    // ---- stage masks 16i x 32j x 3 = 384 float4 ----
    #pragma unroll
    for (int it2 = 0; it2 < 2; ++it2) {
      int f = t + it2 * 256;
      if (f < 384) {
        int ii = f / 24;
        int rem = f - ii * 24;
        *(float4*)(mrp + ii * MRP + rem * 4) =
          *(const float4*)(masks + (long)(i0 + ii) * (NN * 3) + (long)j0 * 3 + rem * 4);
      }
    }
    __syncthreads();   // bar1: masks staged; prev tile's arec readers done

    // ---- QK: wave g = w, both batches, K direct from global ----
    #pragma unroll
    for (int b2 = 0; b2 < 2; ++b2) {
      const short* kbase = b2 ? kbase1 : kbase0;
      #pragma unroll
      for (int jsub = 0; jsub < 2; ++jsub) {
        union { short s[8]; short8 v; } kk;
        #pragma unroll
        for (int z = 0; z < 8; ++z) kk.s[z] = 0;
        if (hq < 2)
          kk.v = *(const short8*)(kbase + (long)(j0 + jsub * 16 + ln) * GD + w * 16 + hq * 8);
        floatx4 at = __builtin_amdgcn_mfma_f32_16x16x32_bf16(qf[b2], kk.v, zf, 0, 0, 0);
        float* ab = arec + b2 * AR1 + (jsub * 16 + ln) * 4 + w;   // [b2][i][j*4+g]
        #pragma unroll
        for (int reg = 0; reg < 4; ++reg)
          ab[(hq * 4 + reg) * ARP] = at[reg];
      }
    }
    __syncthreads();   // bar2: arec ready

    // ---- mix + exp2 + PV: thread = (i=ln, j-octet=hq); mw shared 2b x 2l ----
    {
      float mku[24];
      {
        const float* mb = mrp + ln * MRP + hq * 24;
        #pragma unroll
        for (int q4 = 0; q4 < 6; ++q4)
          *(float4*)(mku + q4 * 4) = *(const float4*)(mb + q4 * 4);
      }
      short8 vf00 = *(const short8*)(vb00 + j0 + hq * 8);
      short8 vf01 = *(const short8*)(vb01 + j0 + hq * 8);
      short8 vf10 = *(const short8*)(vb10 + j0 + hq * 8);
      short8 vf11 = *(const short8*)(vb11 + j0 + hq * 8);
      const float* arA = arec + ln * ARP + hq * 32;
      const float* arB = arec + AR1 + ln * ARP + hq * 32;
      union PS { unsigned u[4]; short8 v; } p00, p01, p10, p11;
      #pragma unroll
      for (int zp = 0; zp < 4; ++zp) {
        float e[8];
        #pragma unroll
        for (int zz = 0; zz < 2; ++zz) {
          int z = zp * 2 + zz;
          floatx4 a0 = *(const floatx4*)(arA + z * 4);
          floatx4 a1 = *(const floatx4*)(arB + z * 4);
          float m0 = mku[z * 3], m1 = mku[z * 3 + 1], m2 = mku[z * 3 + 2];
          float wA0 = m0*ycA[0][0] + m1*ycA[1][0] + m2*ycA[2][0];
          float wA1 = m0*ycA[0][1] + m1*ycA[1][1] + m2*ycA[2][1];
          float wA2 = m0*ycA[0][2] + m1*ycA[1][2] + m2*ycA[2][2];
          float wA3 = m0*ycA[0][3] + m1*ycA[1][3] + m2*ycA[2][3];
          float wB0 = m0*ycB[0][0] + m1*ycB[1][0] + m2*ycB[2][0];
          float wB1 = m0*ycB[0][1] + m1*ycB[1][1] + m2*ycB[2][1];
          float wB2 = m0*ycB[0][2] + m1*ycB[1][2] + m2*ycB[2][2];
          float wB3 = m0*ycB[0][3] + m1*ycB[1][3] + m2*ycB[2][3];
          float s00 = a0[0]*wA0 + a0[1]*wA1 + a0[2]*wA2 + a0[3]*wA3;
          float s01 = a0[0]*wB0 + a0[1]*wB1 + a0[2]*wB2 + a0[3]*wB3;
          float s10 = a1[0]*wA0 + a1[1]*wA1 + a1[2]*wA2 + a1[3]*wA3;
          float s11 = a1[0]*wB0 + a1[1]*wB1 + a1[2]*wB2 + a1[3]*wB3;
          e[zz*4+0] = EXP2(s00); e[zz*4+1] = EXP2(s01);
          e[zz*4+2] = EXP2(s10); e[zz*4+3] = EXP2(s11);
        }
        unsigned u00 = pk2(e[0], e[4]);
        unsigned u01 = pk2(e[1], e[5]);
        unsigned u10 = pk2(e[2], e[6]);
        unsigned u11 = pk2(e[3], e[7]);
        p00.u[zp] = u00; p01.u[zp] = u01; p10.u[zp] = u10; p11.u[zp] = u11;
        // denom from the bf16-rounded values actually fed to PV
        union { unsigned u; float f; } cA, cB;
        cA.u = u00 << 16;          d00 += cA.f;
        cB.u = u00 & 0xffff0000u;  d00 += cB.f;
        cA.u = u01 << 16;          d01 += cA.f;
        cB.u = u01 & 0xffff0000u;  d01 += cB.f;
        cA.u = u10 << 16;          d10 += cA.f;
        cB.u = u10 & 0xffff0000u;  d10 += cB.f;
        cA.u = u11 << 16;          d11 += cA.f;
        cB.u = u11 & 0xffff0000u;  d11 += cB.f;
      }
      pv00 = __builtin_amdgcn_mfma_f32_16x16x32_bf16(p00.v, vf00, pv00, 0, 0, 0);
      pv01 = __builtin_amdgcn_mfma_f32_16x16x32_bf16(p01.v, vf01, pv01, 0, 0, 0);
      pv10 = __builtin_amdgcn_mfma_f32_16x16x32_bf16(p10.v, vf10, pv10, 0, 0, 0);
      pv11 = __builtin_amdgcn_mfma_f32_16x16x32_bf16(p11.v, vf11, pv11, 0, 0, 0);
    }
  }

  // ---- epilogue ----
  #pragma unroll
  for (int reg = 0; reg < 4; ++reg) {
    long row0 = ((long)(sp * BB + b0)) * NN + i0 + hq * 4 + reg;
    long row1 = row0 + NN;
    pnum[row0 * CC + l0 * 16 + ln] = pv00[reg];
    pnum[row0 * CC + l1 * 16 + ln] = pv01[reg];
    pnum[row1 * CC + l0 * 16 + ln] = pv10[reg];
    pnum[row1 * CC + l1 * 16 + ln] = pv11[reg];
  }
  long drow0 = ((long)(sp * BB + b0)) * NN + i0 + ln;
  long drow1 = drow0 + NN;
  pden3[drow0 * 32 + l0 * 4 + hq] = d00;
  pden3[drow0 * 32 + l1 * 4 + hq] = d01;
  pden3[drow1 * 32 + l0 * 4 + hq] = d10;
  pden3[drow1 * 32 + l1 * 4 + hq] = d11;
}

// ---------------- Kernel C: combine partials ----------------
__global__ __launch_bounds__(256) void reduce_kernel(
    const float* __restrict__ pnum, const float* __restrict__ pden3,
    float* __restrict__ out)
{
  int e4 = blockIdx.x * 256 + threadIdx.x;   // float4 index
  int bi = e4 >> 5;                          // token 0..8191
  int l = (e4 & 31) >> 2;
  const float4* p4 = (const float4*)pnum;
  float4 n = {0.f, 0.f, 0.f, 0.f};
  float den = 0.f;
  #pragma unroll
  for (int s = 0; s < SPLIT; ++s) {
    float4 ns = p4[e4 + (long)s * (BB * NN * CC / 4)];
    n.x += ns.x; n.y += ns.y; n.z += ns.z; n.w += ns.w;
    float4 d4 = *(const float4*)(pden3 + ((long)s * BB * NN + bi) * 32 + l * 4);
    den += d4.x + d4.y + d4.z + d4.w;
  }
  float inv = 1.0f / den;
  float4 o;
  o.x = n.x * inv; o.y = n.y * inv; o.z = n.z * inv; o.w = n.w * inv;
  ((float4*)out)[e4] = o;
}

extern "C" void kernel_launch(void* const* d_in, const int* in_sizes, int n_in,
                              void* d_out, int out_size, void* d_ws, size_t ws_size,
                              hipStream_t stream) {
  const float* x         = (const float*)d_in[0];
  const float* masks     = (const float*)d_in[1];
  const float* Wq        = (const float*)d_in[2];
  const float* Wk        = (const float*)d_in[3];
  const float* Wv        = (const float*)d_in[4];
  const float* mask_proj = (const float*)d_in[5];
  float* out = (float*)d_out;

  // ws bytes: qb 1M | kb 1M | vtb 2M | pnum 16M | pden3 4M = 24 MB
  char* wsB = (char*)d_ws;
  short* qb    = (short*)(wsB);
  short* kb    = (short*)(wsB + (1l << 20));
  short* vtb   = (short*)(wsB + (2l << 20));
  float* pnum  = (float*)(wsB + (4l << 20));
  float* pden3 = (float*)(wsB + (20l << 20));

  proj_kernel<<<512, 256, 0, stream>>>(x, Wq, Wk, Wv, qb, kb, vtb);
  attn_kernel<<<(SPLIT * 64) * (BB / 2), 256, 0, stream>>>(qb, kb, vtb, masks,
                                                           mask_proj, pnum, pden3);
  reduce_kernel<<<(BB * NN * CC / 4) / 256, 256, 0, stream>>>(pnum, pden3, out);
}